// Round 9
// baseline (140.657 us; speedup 1.0000x reference)
//
#include <hip/hip_runtime.h>
#include <hip/hip_cooperative_groups.h>
#include <math.h>

namespace cg = cooperative_groups;

#define TH 512                      // 8 waves/block
#define WT 4                        // 4 query tiles/wave
#define QPB (8 * WT * 32)           // 1024 queries per block
#define SEGS 8                      // db segments (grid.y)
#define SCH 64                      // chunks per stage = whole segment (64KB)
#define POISON 0xAAAAAAAAu

typedef __bf16 bf16x8 __attribute__((ext_vector_type(8)));
typedef float  f32x16 __attribute__((ext_vector_type(16)));

// R27: model revision from R24/R26 -- MFMA executes ON the SIMD ALUs
// (MfmaUtil+VALUBusy ~ 93% mutually exclusive; 4 vs 2 waves/SIMD neutral):
// the hot loop is at ~93% of the SIMD ISSUE roofline (416 cyc/pair model
// matches L=14.2us).  Loop is done.  Remaining controllable time: reduce
// dispatch + gaps + part traffic (~5-7us).  This round: ONE cooperative
// kernel -- phase 1 = R22 core verbatim with atomicMin epilogue (poison =
// +inf init, R21-validated numerics), one grid.sync(), phase 2 = finalize
// DISTRIBUTED over all 256 blocks (128 queries each; R21's mistake was 1
// block), last-block elect (poison-aware counter) folds 256 block sums.
// Fallback to the R22 two-kernel path if cooperative launch errors.
//
// Split-bf16 MFMA 32x32x16, db on A / queries on B (R15-validated):
//  kg = lane>>5; A row = db idx = lane&31; B col = query idx = lane&31.
//  kg0 (k0-7):  A(db)={th(x,y,z), th(x,y,z), 1, 1}
//               B(q) ={-qh(x,y,z), -ql(x,y,z), q2h_hi, q2h_lo}
//  kg1 (k8-15): A(db)={tl(x,y,z), t2h_hi, t2h_lo, tl(x,y,z)}
//               B(q) ={-qh(x,y,z), 1, 1, -ql(x,y,z)}
//  => D = ||q||^2/2 + ||t||^2/2 - q.t = sq_dist/2
// C/D: col = query = lane&31, row = db = (e&3)+8*(e>>2)+4*kg  [m74/m101].

__device__ __forceinline__ void chamfer_core(
        const float* __restrict__ pred, int n,
        const float* __restrict__ target, int m,
        unsigned* __restrict__ dminAll) {
    const int dir = blockIdx.z;
    const float* __restrict__ q  = dir ? target : pred;
    const float* __restrict__ db = dir ? pred : target;
    const int nq  = dir ? m : n;
    const int ndb = dir ? n : m;
    unsigned* __restrict__ dmin = dminAll + (dir ? n : 0);

    const int tid  = threadIdx.x;
    const int lane = tid & 63;
    const int wave = tid >> 6;         // 0..7
    const int kg   = lane >> 5;        // k-group 0..1
    const int rc   = lane & 31;        // A db-row / B query-col
    const __bf16 one = (__bf16)1.0f;

    // ---- Query fragments (B operand, once per block) ----
    bf16x8 qfr[WT];
    f32x16 rmin[WT];
    const int qtb = blockIdx.x * QPB + wave * (WT * 32);
#pragma unroll
    for (int t = 0; t < WT; ++t) {
        int qi = qtb + t * 32 + rc;
        int qc = (qi < nq) ? qi : 0;              // clamp; OOB never stored
        float qx = -q[qc * 3 + 0], qy = -q[qc * 3 + 1], qz = -q[qc * 3 + 2];
        __bf16 xh = (__bf16)qx; __bf16 xl = (__bf16)(qx - (float)xh);
        __bf16 yh = (__bf16)qy; __bf16 yl = (__bf16)(qy - (float)yh);
        __bf16 zh = (__bf16)qz; __bf16 zl = (__bf16)(qz - (float)zh);
        float q2h = 0.5f * fmaf(qz, qz, fmaf(qy, qy, qx * qx));
        __bf16 hh = (__bf16)q2h; __bf16 hl = (__bf16)(q2h - (float)hh);
        bf16x8 b0 = {xh, yh, zh, xl, yl, zl, hh, hl};
        bf16x8 b1 = {xh, yh, zh, one, one, xl, yl, zl};
        qfr[t] = kg ? b1 : b0;
        rmin[t] = 3.0e38f;
    }
    const f32x16 zf = 0.0f;

    // ---- db segment, single-staged via LDS (A-operand fragments) ----
    const int nchunks = (ndb + 31) >> 5;          // 32-pt chunks
    const int cpseg = (nchunks + SEGS - 1) / SEGS;
    const int c_begin = blockIdx.y * cpseg;
    const int c_end = min(nchunks, c_begin + cpseg);

    // [chunk][kg(2)][row(32)] uint4 -> lane reads sB[c*64 + lane]:
    // 64 lanes x 16B fully linear = conflict-free b128.
    __shared__ uint4 sB[SCH * 64];     // 64 KB; whole segment, one stage

#define MFMA_(A, T) __builtin_amdgcn_mfma_f32_32x32x16_bf16((A), qfr[T], zf, 0, 0, 0)
#define MIN3T(T, D0, D1) do { _Pragma("unroll")                               \
        for (int e = 0; e < 16; ++e)                                          \
            rmin[T][e] = fminf(fminf(rmin[T][e], (D0)[e]), (D1)[e]); } while (0)

    for (int c0 = c_begin; c0 < c_end; c0 += SCH) {
        const int csub = min(SCH, c_end - c0);
        __syncthreads();
        for (int pl = tid; pl < csub * 32; pl += TH) {
            int gp = c0 * 32 + pl;
            float tx = 0.f, ty = 0.f, tz = 0.f, h = 1.0e30f;
            if (gp < ndb) {
                tx = db[gp * 3 + 0]; ty = db[gp * 3 + 1]; tz = db[gp * 3 + 2];
                h = 0.5f * fmaf(tz, tz, fmaf(ty, ty, tx * tx));
            }
            __bf16 xh = (__bf16)tx; __bf16 xl = (__bf16)(tx - (float)xh);
            __bf16 yh = (__bf16)ty; __bf16 yl = (__bf16)(ty - (float)yh);
            __bf16 zh = (__bf16)tz; __bf16 zl = (__bf16)(tz - (float)zh);
            __bf16 hh = (__bf16)h;  __bf16 hl = (__bf16)(h - (float)hh);
            bf16x8 a0 = {xh, yh, zh, xh, yh, zh, one, one};
            bf16x8 a1 = {xl, yl, zl, hh, hl, xl, yl, zl};
            int ch = pl >> 5, cp = pl & 31;
            sB[ch * 64 + cp]      = __builtin_bit_cast(uint4, a0);
            sB[ch * 64 + 32 + cp] = __builtin_bit_cast(uint4, a1);
        }
        __syncthreads();

        // Chunk pairs: 2 ds_read_b128 + 8 independent MFMA + 64 v_min3.
        int cc = 0;
#pragma unroll 2
        for (; cc + 2 <= csub; cc += 2) {
            bf16x8 aA = __builtin_bit_cast(bf16x8, sB[cc * 64 + lane]);
            bf16x8 aB = __builtin_bit_cast(bf16x8, sB[cc * 64 + 64 + lane]);
            f32x16 dA0 = MFMA_(aA, 0);
            f32x16 dB0 = MFMA_(aB, 0);
            f32x16 dA1 = MFMA_(aA, 1);
            f32x16 dB1 = MFMA_(aB, 1);
            MIN3T(0, dA0, dB0);
            f32x16 dA2 = MFMA_(aA, 2);
            f32x16 dB2 = MFMA_(aB, 2);
            MIN3T(1, dA1, dB1);
            f32x16 dA3 = MFMA_(aA, 3);
            f32x16 dB3 = MFMA_(aB, 3);
            MIN3T(2, dA2, dB2);
            MIN3T(3, dA3, dB3);
        }
        if (cc < csub) {                           // odd tail chunk
            bf16x8 aA = __builtin_bit_cast(bf16x8, sB[cc * 64 + lane]);
#pragma unroll
            for (int t = 0; t < WT; ++t) {
                f32x16 d0 = MFMA_(aA, t);
                rmin[t] = __builtin_elementwise_min(rmin[t], d0);
            }
        }
    }
#undef MFMA_
#undef MIN3T

    // ---- Epilogue: 15 in-lane mins + shfl_xor(32), then atomicMin ----
    // dmin poison-init: 0xAAAAAAAA (uint) > any finite positive float bits;
    // uint min == float min for x >= 0 (R21-validated numerics).
#pragma unroll
    for (int t = 0; t < WT; ++t) {
        f32x16 r = rmin[t];
        float v = r[0];
#pragma unroll
        for (int e = 1; e < 16; ++e) v = fminf(v, r[e]);
        v = fminf(v, __shfl_xor(v, 32, 64));       // combine kg halves
        int qi = qtb + t * 32 + rc;
        if (kg == 0 && qi < nq)
            atomicMin(&dmin[qi], __float_as_uint(fmaxf(0.0f, v)));
    }
}

__device__ __forceinline__ void finalize_phase(
        int n, int m, const unsigned* __restrict__ dminAll,
        float* __restrict__ bsF, float* __restrict__ bsB,
        unsigned* __restrict__ counter, float* __restrict__ out) {
    const int tid = threadIdx.x;
    const int lane = tid & 63, wv = tid >> 6;
    const int flat = blockIdx.x +
                     gridDim.x * (blockIdx.y + gridDim.y * blockIdx.z);
    const int nblocks = gridDim.x * gridDim.y * gridDim.z;

    // Each block finalizes 128 queries of the combined [0, n+m) range.
    float vF = 0.0f, vB = 0.0f;
    if (tid < 128) {
        int j = flat * 128 + tid;
        if (j < n + m) {
            unsigned u = __hip_atomic_load(&dminAll[j],
                    __ATOMIC_RELAXED, __HIP_MEMORY_SCOPE_AGENT);
            float r = sqrtf(2.0f * fmaxf(0.0f, __uint_as_float(u)));
            if (j < n) vF = r; else vB = r;
        }
    }
#pragma unroll
    for (int off = 32; off > 0; off >>= 1) {
        vF += __shfl_down(vF, off, 64);
        vB += __shfl_down(vB, off, 64);
    }
    __shared__ float wF[8], wB[8];
    __shared__ unsigned s_last;
    if (lane == 0) { wF[wv] = vF; wB[wv] = vB; }
    __syncthreads();
    if (tid == 0) {
        float tF = 0.f, tB = 0.f;
#pragma unroll
        for (int w = 0; w < 8; ++w) { tF += wF[w]; tB += wB[w]; }
        bsF[flat] = tF; bsB[flat] = tB;
        __threadfence();
        unsigned done = atomicAdd(counter, 1u);
        unsigned nb1 = (unsigned)(nblocks - 1);
        s_last = (done == nb1) || (done == POISON + nb1);
    }
    __syncthreads();
    if (!s_last) return;
    __threadfence();                   // acquire side

    // Last block folds 256 block sums (waves 0-3 active, 64 each).
    float pF = 0.0f, pB = 0.0f;
    if (tid < 256) {
        pF = __uint_as_float(__hip_atomic_load((const unsigned*)&bsF[tid],
                __ATOMIC_RELAXED, __HIP_MEMORY_SCOPE_AGENT));
        pB = __uint_as_float(__hip_atomic_load((const unsigned*)&bsB[tid],
                __ATOMIC_RELAXED, __HIP_MEMORY_SCOPE_AGENT));
    }
#pragma unroll
    for (int off = 32; off > 0; off >>= 1) {
        pF += __shfl_down(pF, off, 64);
        pB += __shfl_down(pB, off, 64);
    }
    __shared__ float w2F[4], w2B[4];
    if (lane == 0 && wv < 4) { w2F[wv] = pF; w2B[wv] = pB; }
    __syncthreads();
    if (tid == 0) {
        float tF = w2F[0] + w2F[1] + w2F[2] + w2F[3];
        float tB = w2B[0] + w2B[1] + w2B[2] + w2B[3];
        out[0] = 0.5f * (tF / (float)n + tB / (float)m);
    }
}

__global__ __launch_bounds__(TH, 2) void chamfer_coop_kernel(
        const float* __restrict__ pred, int n,
        const float* __restrict__ target, int m,
        unsigned* __restrict__ dminAll,
        float* __restrict__ bsF, float* __restrict__ bsB,
        unsigned* __restrict__ counter, float* __restrict__ out) {
    chamfer_core(pred, n, target, m, dminAll);
    __threadfence();
    cg::this_grid().sync();
    finalize_phase(n, m, dminAll, bsF, bsB, counter, out);
}

// ---- Fallback path (non-cooperative): R22 two-kernel structure ----
__global__ __launch_bounds__(TH, 2) void chamfer_fb_kernel(
        const float* __restrict__ pred, int n,
        const float* __restrict__ target, int m,
        unsigned* __restrict__ dminAll) {
    chamfer_core(pred, n, target, m, dminAll);
}

__global__ __launch_bounds__(256) void reduce_fb_kernel(
        const unsigned* __restrict__ dminAll,
        float* __restrict__ bsF, float* __restrict__ bsB,
        unsigned* __restrict__ counter,
        int n, int m, float* __restrict__ out, int nblocks) {
    const int tid = threadIdx.x;
    const int j = blockIdx.x * 256 + tid;        // [0, n+m)
    float vF = 0.0f, vB = 0.0f;
    if (j < n + m) {
        float r = sqrtf(2.0f * fmaxf(0.0f, __uint_as_float(dminAll[j])));
        if (j < n) vF = r; else vB = r;
    }
    for (int off = 32; off > 0; off >>= 1) {
        vF += __shfl_down(vF, off, 64);
        vB += __shfl_down(vB, off, 64);
    }
    __shared__ float wF[4], wB[4];
    __shared__ unsigned s_last;
    int lane = tid & 63, wv = tid >> 6;
    if (lane == 0) { wF[wv] = vF; wB[wv] = vB; }
    __syncthreads();
    if (tid == 0) {
        bsF[blockIdx.x] = wF[0] + wF[1] + wF[2] + wF[3];
        bsB[blockIdx.x] = wB[0] + wB[1] + wB[2] + wB[3];
        __threadfence();
        unsigned done = atomicAdd(counter, 1u);
        unsigned nb1 = (unsigned)(nblocks - 1);
        s_last = (done == nb1) || (done == POISON + nb1);
    }
    __syncthreads();
    if (!s_last) return;
    __threadfence();

    float pF = 0.0f, pB = 0.0f;
    if (tid < 128) {
        pF = __uint_as_float(__hip_atomic_load((const unsigned*)&bsF[tid],
                __ATOMIC_RELAXED, __HIP_MEMORY_SCOPE_AGENT));
        pB = __uint_as_float(__hip_atomic_load((const unsigned*)&bsB[tid],
                __ATOMIC_RELAXED, __HIP_MEMORY_SCOPE_AGENT));
    }
    for (int off = 32; off > 0; off >>= 1) {
        pF += __shfl_down(pF, off, 64);
        pB += __shfl_down(pB, off, 64);
    }
    __shared__ float w2F[2], w2B[2];
    if (lane == 0 && wv < 2) { w2F[wv] = pF; w2B[wv] = pB; }
    __syncthreads();
    if (tid == 0)
        out[0] = 0.5f * ((w2F[0] + w2F[1]) / (float)n +
                         (w2B[0] + w2B[1]) / (float)m);
}

extern "C" void kernel_launch(void* const* d_in, const int* in_sizes, int n_in,
                              void* d_out, int out_size, void* d_ws, size_t ws_size,
                              hipStream_t stream) {
    const float* pred   = (const float*)d_in[0];
    const float* target = (const float*)d_in[1];
    int n = in_sizes[0] / 3;   // 16384
    int m = in_sizes[1] / 3;   // 16384

    unsigned* dminAll = (unsigned*)d_ws;          // n+m uints (poison=+inf)
    float* bsF = (float*)(dminAll + n + m);       // 256 floats
    float* bsB = bsF + 256;                       // 256 floats
    unsigned* counter = (unsigned*)(bsB + 256);   // poison-aware
    float* out = (float*)d_out;

    int nmax = (n > m) ? n : m;
    int gx = (nmax + QPB - 1) / QPB;              // 16
    dim3 grid(gx, SEGS, 2);                       // 256 blocks = 1/CU
    dim3 blk(TH);

    void* args[] = { (void*)&pred, (void*)&n, (void*)&target, (void*)&m,
                     (void*)&dminAll, (void*)&bsF, (void*)&bsB,
                     (void*)&counter, (void*)&out };
    hipError_t err = hipLaunchCooperativeKernel(
            (const void*)chamfer_coop_kernel, grid, blk, args, 0, stream);
    if (err != hipSuccess) {
        // Fallback: two-kernel path (R22 structure, atomicMin variant)
        chamfer_fb_kernel<<<grid, blk, 0, stream>>>(pred, n, target, m,
                                                    dminAll);
        int nb = (n + m + 255) / 256;             // 128
        reduce_fb_kernel<<<nb, 256, 0, stream>>>(dminAll, bsF, bsB, counter,
                                                 n, m, out, nb);
    }
}

// Round 10
// 77.326 us; speedup vs baseline: 1.8190x; 1.8190x over previous
//
#include <hip/hip_runtime.h>
#include <math.h>

#define TH 512                      // 8 waves/block
#define WT 4                        // 4 query tiles/wave
#define QPB (8 * WT * 32)           // 1024 queries per block
#define SEGS 8                      // db segments (grid.y)
#define SCH 64                      // chunks per LDS stage = whole segment
#define POISON 0xAAAAAAAAu

typedef __bf16 bf16x8 __attribute__((ext_vector_type(8)));
typedef float  f32x16 __attribute__((ext_vector_type(16)));

// R28: RESTORE BEST (R22, 77.29us).  Session ledger (all measured):
//  - fill 39.7us: harness 256MiB ws re-poison at 84% HBM peak (own roofline)
//  - chamfer ~26us: L=14.2us/pass at 93% SIMD ISSUE roofline (R24 REPS=4
//    counters: MfmaUtil 41.5 + VALUBusy 51.6, mutually exclusive -- MFMA
//    issues on the SIMD ALUs; 416cyc/pair model matches), S~12us launch +
//    cache-cold staging latency (poison flushes L2/L3 each iteration)
//  - reduce ~5us: launch-dominated; gaps/restores ~6.6us: harness-owned
// Falsified alternatives: WT={1,2,4}, 2 vs 4 waves/SIMD (R26 neutral),
// pre-packed frags + global_load_lds (R23 +4), SW pipeline (R19 +4),
// asm pins (R22 neutral), atomicMin epilogue (+45us: device-scope RMW +
// fence on 8 non-coherent XCDs -- R21/R27 identical 71.4/71.9 despite
// opposite finalize structures), cooperative single-kernel (R27).
// __launch_bounds__ trap (R25): (512,4) caps 64 arch VGPRs -> rmin spills,
// 12.6GB scratch, 42x slowdown.  (512,2) -> 92 VGPRs, no spill.
//
// Split-bf16 MFMA 32x32x16, db on A / queries on B (R15-validated):
//  kg = lane>>5; A row = db idx = lane&31; B col = query idx = lane&31.
//  kg0 (k0-7):  A(db)={th(x,y,z), th(x,y,z), 1, 1}
//               B(q) ={-qh(x,y,z), -ql(x,y,z), q2h_hi, q2h_lo}
//  kg1 (k8-15): A(db)={tl(x,y,z), t2h_hi, t2h_lo, tl(x,y,z)}
//               B(q) ={-qh(x,y,z), 1, 1, -ql(x,y,z)}
//  => D = ||q||^2/2 + ||t||^2/2 - q.t = sq_dist/2
// C/D: col = query = lane&31, row = db = (e&3)+8*(e>>2)+4*kg  [m74/m101].
__global__ __launch_bounds__(TH, 2) void chamfer_mfma_kernel(
        const float* __restrict__ pred, int n,
        const float* __restrict__ target, int m,
        float* __restrict__ partF, float* __restrict__ partB) {
    const int dir = blockIdx.z;
    const float* __restrict__ q  = dir ? target : pred;
    const float* __restrict__ db = dir ? pred : target;
    const int nq  = dir ? m : n;
    const int ndb = dir ? n : m;
    float* __restrict__ outPart = dir ? partB : partF;

    const int tid  = threadIdx.x;
    const int lane = tid & 63;
    const int wave = tid >> 6;         // 0..7
    const int kg   = lane >> 5;        // k-group 0..1
    const int rc   = lane & 31;        // A db-row / B query-col
    const __bf16 one = (__bf16)1.0f;

    // ---- Query fragments (B operand, once per block) ----
    bf16x8 qfr[WT];
    f32x16 rmin[WT];
    const int qtb = blockIdx.x * QPB + wave * (WT * 32);
#pragma unroll
    for (int t = 0; t < WT; ++t) {
        int qi = qtb + t * 32 + rc;
        int qc = (qi < nq) ? qi : 0;              // clamp; OOB never stored
        float qx = -q[qc * 3 + 0], qy = -q[qc * 3 + 1], qz = -q[qc * 3 + 2];
        __bf16 xh = (__bf16)qx; __bf16 xl = (__bf16)(qx - (float)xh);
        __bf16 yh = (__bf16)qy; __bf16 yl = (__bf16)(qy - (float)yh);
        __bf16 zh = (__bf16)qz; __bf16 zl = (__bf16)(qz - (float)zh);
        float q2h = 0.5f * fmaf(qz, qz, fmaf(qy, qy, qx * qx));
        __bf16 hh = (__bf16)q2h; __bf16 hl = (__bf16)(q2h - (float)hh);
        bf16x8 b0 = {xh, yh, zh, xl, yl, zl, hh, hl};
        bf16x8 b1 = {xh, yh, zh, one, one, xl, yl, zl};
        qfr[t] = kg ? b1 : b0;
        rmin[t] = 3.0e38f;
    }
    const f32x16 zf = 0.0f;

    // ---- db segment, single-staged via LDS (A-operand fragments) ----
    const int nchunks = (ndb + 31) >> 5;          // 32-pt chunks
    const int cpseg = (nchunks + SEGS - 1) / SEGS;
    const int c_begin = blockIdx.y * cpseg;
    const int c_end = min(nchunks, c_begin + cpseg);

    // [chunk][kg(2)][row(32)] uint4 -> lane reads sB[c*64 + lane]:
    // 64 lanes x 16B fully linear = conflict-free b128.
    __shared__ uint4 sB[SCH * 64];     // 64 KB; whole segment, one stage

#define MFMA_(A, T) __builtin_amdgcn_mfma_f32_32x32x16_bf16((A), qfr[T], zf, 0, 0, 0)
#define MIN3T(T, D0, D1) do { _Pragma("unroll")                               \
        for (int e = 0; e < 16; ++e)                                          \
            rmin[T][e] = fminf(fminf(rmin[T][e], (D0)[e]), (D1)[e]); } while (0)

    for (int c0 = c_begin; c0 < c_end; c0 += SCH) {
        const int csub = min(SCH, c_end - c0);
        __syncthreads();
        for (int pl = tid; pl < csub * 32; pl += TH) {
            int gp = c0 * 32 + pl;
            float tx = 0.f, ty = 0.f, tz = 0.f, h = 1.0e30f;
            if (gp < ndb) {
                tx = db[gp * 3 + 0]; ty = db[gp * 3 + 1]; tz = db[gp * 3 + 2];
                h = 0.5f * fmaf(tz, tz, fmaf(ty, ty, tx * tx));
            }
            __bf16 xh = (__bf16)tx; __bf16 xl = (__bf16)(tx - (float)xh);
            __bf16 yh = (__bf16)ty; __bf16 yl = (__bf16)(ty - (float)yh);
            __bf16 zh = (__bf16)tz; __bf16 zl = (__bf16)(tz - (float)zh);
            __bf16 hh = (__bf16)h;  __bf16 hl = (__bf16)(h - (float)hh);
            bf16x8 a0 = {xh, yh, zh, xh, yh, zh, one, one};
            bf16x8 a1 = {xl, yl, zl, hh, hl, xl, yl, zl};
            int ch = pl >> 5, cp = pl & 31;
            sB[ch * 64 + cp]      = __builtin_bit_cast(uint4, a0);
            sB[ch * 64 + 32 + cp] = __builtin_bit_cast(uint4, a1);
        }
        __syncthreads();

        // Chunk pairs: 2 ds_read_b128 + 8 independent MFMA + 64 v_min3.
        int cc = 0;
#pragma unroll 2
        for (; cc + 2 <= csub; cc += 2) {
            bf16x8 aA = __builtin_bit_cast(bf16x8, sB[cc * 64 + lane]);
            bf16x8 aB = __builtin_bit_cast(bf16x8, sB[cc * 64 + 64 + lane]);
            f32x16 dA0 = MFMA_(aA, 0);
            f32x16 dB0 = MFMA_(aB, 0);
            f32x16 dA1 = MFMA_(aA, 1);
            f32x16 dB1 = MFMA_(aB, 1);
            MIN3T(0, dA0, dB0);
            f32x16 dA2 = MFMA_(aA, 2);
            f32x16 dB2 = MFMA_(aB, 2);
            MIN3T(1, dA1, dB1);
            f32x16 dA3 = MFMA_(aA, 3);
            f32x16 dB3 = MFMA_(aB, 3);
            MIN3T(2, dA2, dB2);
            MIN3T(3, dA3, dB3);
        }
        if (cc < csub) {                           // odd tail chunk
            bf16x8 aA = __builtin_bit_cast(bf16x8, sB[cc * 64 + lane]);
#pragma unroll
            for (int t = 0; t < WT; ++t) {
                f32x16 d0 = MFMA_(aA, t);
                rmin[t] = __builtin_elementwise_min(rmin[t], d0);
            }
        }
    }
#undef MFMA_
#undef MIN3T

    // ---- Epilogue: rows are db -> 15 in-lane mins + 1 shfl_xor(32) ----
#pragma unroll
    for (int t = 0; t < WT; ++t) {
        f32x16 r = rmin[t];
        float v = r[0];
#pragma unroll
        for (int e = 1; e < 16; ++e) v = fminf(v, r[e]);
        v = fminf(v, __shfl_xor(v, 32, 64));       // combine kg halves
        int qi = qtb + t * 32 + rc;
        if (kg == 0 && qi < nq)                    // 32 coalesced stores/tile
            outPart[(size_t)blockIdx.y * nq + qi] = fmaxf(0.0f, v);
    }
}

// Fused reduce: 128 blocks; thread j owns one query: min over SEGS partials,
// sqrt(2*v), block-sum -> partials[b]; poison-aware last block finalizes.
__global__ __launch_bounds__(256) void reduce_kernel(
        const float* __restrict__ partF, const float* __restrict__ partB,
        float* __restrict__ partials, unsigned* __restrict__ counter,
        int n, int m, float* __restrict__ out, int nblocks) {
    const int tid = threadIdx.x;
    const int j = blockIdx.x * 256 + tid;        // flat query id in [0, n+m)
    const bool isF = j < n;
    const float* __restrict__ part = isF ? partF : partB;
    const int qn = isF ? n : m;
    const int qi = isF ? j : j - n;

    float v = 3.0e38f;
#pragma unroll
    for (int s = 0; s < SEGS; ++s)
        v = fminf(v, part[(size_t)s * qn + qi]);
    v = sqrtf(2.0f * fmaxf(0.0f, v));

    for (int off = 32; off > 0; off >>= 1) v += __shfl_down(v, off, 64);
    __shared__ float w[4];
    __shared__ unsigned s_last;
    int lane = tid & 63, wv = tid >> 6;
    if (lane == 0) w[wv] = v;
    __syncthreads();
    if (tid == 0) {
        partials[blockIdx.x] = w[0] + w[1] + w[2] + w[3];
        __threadfence();
        unsigned done = atomicAdd(counter, 1u);
        unsigned nb1 = (unsigned)(nblocks - 1);
        s_last = (done == nb1) || (done == POISON + nb1);
    }
    __syncthreads();
    if (!s_last) return;
    __threadfence();                   // acquire side

    // partials[0..63] = F blocks, [64..127] = B blocks. wave0 sums F, wave1 B.
    float p = 0.0f;
    if (tid < 128)
        p = __uint_as_float(__hip_atomic_load(
                (const unsigned*)&partials[tid],
                __ATOMIC_RELAXED, __HIP_MEMORY_SCOPE_AGENT));
    for (int off = 32; off > 0; off >>= 1) p += __shfl_down(p, off, 64);
    __shared__ float w2[2];
    if (tid == 0)  w2[0] = p;
    if (tid == 64) w2[1] = p;
    __syncthreads();
    if (tid == 0)
        out[0] = 0.5f * (w2[0] / (float)n + w2[1] / (float)m);
}

extern "C" void kernel_launch(void* const* d_in, const int* in_sizes, int n_in,
                              void* d_out, int out_size, void* d_ws, size_t ws_size,
                              hipStream_t stream) {
    const float* pred   = (const float*)d_in[0];
    const float* target = (const float*)d_in[1];
    const int n = in_sizes[0] / 3;   // 16384
    const int m = in_sizes[1] / 3;   // 16384

    float* partF = (float*)d_ws;                  // SEGS*n floats
    float* partB = partF + (size_t)SEGS * n;      // SEGS*m floats
    float* partials = partB + (size_t)SEGS * m;   // 128 floats
    unsigned* counter = (unsigned*)(partials + 128);
    float* out = (float*)d_out;

    int nmax = (n > m) ? n : m;
    int gx = (nmax + QPB - 1) / QPB;         // 16
    dim3 grid(gx, SEGS, 2);                  // 256 blocks -> 1/CU, one round
    chamfer_mfma_kernel<<<grid, TH, 0, stream>>>(pred, n, target, m, partF, partB);

    int nb = (n + m) / 256;                  // 128; F in [0,64), B in [64,128)
    reduce_kernel<<<nb, 256, 0, stream>>>(partF, partB, partials, counter,
                                          n, m, out, nb);
}